// Round 7
// baseline (15.020 us; speedup 1.0000x reference)
//
#include <hip/hip_runtime.h>
#include <math.h>

// ---- problem constants ----
// SIZE=(60,270,480); CHANNELS=14; GRIDS: (60,16,16,8),(30,8,8,4),(15,4,4,2)
// IDX_MAX=(60,3,5) -> patch=(1,90,96); PADDING=(0,1,1) -> ppad=(1,92,98)
// t_embed: [64][1][92][98][14] = 8,078,336 f32 ; t_manip: [64][16]

#define N_PATCH 64
#define PPAD_H 92
#define PPAD_W 98
#define CH 14
#define PIX_PER_PATCH (PPAD_H * PPAD_W)        // 9016
#define ROWS_PER_BLOCK 12
#define BLOCKS_PER_PATCH 8                     // 7*12 + 8 = 92 rows
#define ELEMS_PER_PATCH (PIX_PER_PATCH * CH)   // 126224
#define ELEMS_PER_ROW (PPAD_W * CH)            // 1372
#define F4_PER_CHUNK (2 * ELEMS_PER_ROW / 4)   // 686 (chunk = 2 rows)
#define TOTAL_EMBED (N_PATCH * ELEMS_PER_PATCH)
#define TOTAL_MANIP (N_PATCH * 16)

// per-row V-record layout (elements): L0 [0,48)=6cells*8ch, L1 [48,64)=4*4, L2 [64,70)=3*2
#define RB_STRIDE 72   // padded, 16B-aligned rows
#define L1_OFF 48
#define L2_OFF 64
#define V_ENTRIES (ROWS_PER_BLOCK * 70)        // 840

__device__ __forceinline__ float lerpf(float a, float b, float f) {
    return a + f * (b - a);
}

// first (leftmost) clamped w-cell for this patch at a given level
__device__ __forceinline__ int wcell0(int rw0, float sw, int Wg) {
    float x = ((float)rw0 + 0.5f) * sw - 0.5f;
    int w0 = (int)floorf(x);
    return min(max(w0, 0), Wg - 1);
}

__global__ __launch_bounds__(256) void embed_kernel(
    const int* __restrict__ idx,
    const float* __restrict__ g0,
    const float* __restrict__ g1,
    const float* __restrict__ g2,
    float* __restrict__ out)
{
    __shared__ __align__(16) float s_V[ROWS_PER_BLOCK * RB_STRIDE];  // 3.4 KB
    __shared__ float4 s_wl[3][PPAD_W];                               // 4.7 KB
    __shared__ __align__(16) float s_bufA[2 * ELEMS_PER_ROW];        // 11 KB
    __shared__ __align__(16) float s_bufB[2 * ELEMS_PER_ROW];        // 11 KB

    const int tid = threadIdx.x;
    const int bx  = blockIdx.x;
    const int n   = blockIdx.y;
    const int it  = idx[3 * n + 0];
    const int ih  = idx[3 * n + 1];
    const int iw  = idx[3 * n + 2];
    const int rw0 = iw * 96 - 1;
    const int row0 = bx * ROWS_PER_BLOCK;

    const float sw0 = (float)((double)16 / 480.0);
    const float sw1 = (float)((double)8  / 480.0);
    const float sw2 = (float)((double)4  / 480.0);
    const float sh0 = (float)((double)16 / 270.0);
    const float sh1 = (float)((double)8  / 270.0);
    const float sh2 = (float)((double)4  / 270.0);

    // ---- fused manip (one block only) ----
    if (bx == 0 && n == 0) {
        float* om = out + TOTAL_EMBED;
        for (int e = tid; e < TOTAL_MANIP; e += 256) {
            int nn = e >> 4;
            int j  = e & 15;
            int l  = j & 7;
            float base = (float)M_PI * (float)(1 << l);  // fl32(2^l*pi), pow2 exact
            float v = (float)idx[3 * nn + 0] * base;     // f32 mul = reference
            double dv = (double)v;
            om[e] = (float)((j < 8) ? sin(dv) : cos(dv));
        }
    }

    // ---- build per-row V tables for all 12 rows (h,t-lerped, row-mask folded) ----
    const int C0_0 = wcell0(rw0, sw0, 16);
    const int C0_1 = wcell0(rw0, sw1, 8);
    const int C0_2 = wcell0(rw0, sw2, 4);
    for (int e = tid; e < V_ENTRIES; e += 256) {
        int row = e / 70;
        int off = e - 70 * row;
        int rh  = ih * 90 + row0 + row - 1;
        float mh = ((unsigned)rh < 270u) ? 1.0f : 0.0f;
        float v;
        if (off < L1_OFF) {
            // L0: 6 cells x 8 ch; T identity (t = it exactly), h-lerp only
            int cell = off >> 3, chn = off & 7;
            float xh = ((float)rh + 0.5f) * sh0 - 0.5f;
            float ff = floorf(xh);
            float fh = xh - ff;
            int h0 = (int)ff;
            int h0c = min(max(h0, 0), 15), h1c = min(h0 + 1, 15);
            int cw = min(C0_0 + cell, 15);
            const float* base = g0 + (size_t)it * 2048;
            float a = base[(h0c * 16 + cw) * 8 + chn];
            float b = base[(h1c * 16 + cw) * 8 + chn];
            v = mh * lerpf(a, b, fh);
        } else if (off < L2_OFF) {
            // L1: 4 cells x 4 ch; t-lerp + h-lerp
            int o = off - L1_OFF;
            int cell = o >> 2, chn = o & 3;
            float xh = ((float)rh + 0.5f) * sh1 - 0.5f;
            float ff = floorf(xh);
            float fh = xh - ff;
            int h0 = (int)ff;
            int h0c = min(max(h0, 0), 7), h1c = min(h0 + 1, 7);
            float xt = ((float)it + 0.5f) * 0.5f - 0.5f;   // 30/60 exact
            float ftf = floorf(xt);
            float ft  = xt - ftf;
            int t0 = (int)ftf;
            int t0c = min(max(t0, 0), 29), t1c = min(t0 + 1, 29);
            int cw = min(C0_1 + cell, 7);
            float a00 = g1[((t0c * 8 + h0c) * 8 + cw) * 4 + chn];
            float a01 = g1[((t0c * 8 + h1c) * 8 + cw) * 4 + chn];
            float a10 = g1[((t1c * 8 + h0c) * 8 + cw) * 4 + chn];
            float a11 = g1[((t1c * 8 + h1c) * 8 + cw) * 4 + chn];
            v = mh * lerpf(lerpf(a00, a01, fh), lerpf(a10, a11, fh), ft);
        } else {
            // L2: 3 cells x 2 ch
            int o = off - L2_OFF;
            int cell = o >> 1, chn = o & 1;
            float xh = ((float)rh + 0.5f) * sh2 - 0.5f;
            float ff = floorf(xh);
            float fh = xh - ff;
            int h0 = (int)ff;
            int h0c = min(max(h0, 0), 3), h1c = min(h0 + 1, 3);
            float xt = ((float)it + 0.5f) * 0.25f - 0.5f;  // 15/60 exact
            float ftf = floorf(xt);
            float ft  = xt - ftf;
            int t0 = (int)ftf;
            int t0c = min(max(t0, 0), 14), t1c = min(t0 + 1, 14);
            int cw = min(C0_2 + cell, 3);
            float a00 = g2[((t0c * 4 + h0c) * 4 + cw) * 2 + chn];
            float a01 = g2[((t0c * 4 + h1c) * 4 + cw) * 2 + chn];
            float a10 = g2[((t1c * 4 + h0c) * 4 + cw) * 2 + chn];
            float a11 = g2[((t1c * 4 + h1c) * 4 + cw) * 2 + chn];
            v = mh * lerpf(lerpf(a00, a01, fh), lerpf(a10, a11, fh), ft);
        }
        s_V[row * RB_STRIDE + off] = v;
    }

    // ---- per-w LUT: (offA, offB, fw, mask) per level, offsets into V record ----
    for (int i = tid; i < 3 * PPAD_W; i += 256) {
        int lvl = (i >= PPAD_W) + (i >= 2 * PPAD_W);
        int ww  = i - PPAD_W * lvl;
        int Wg  = (lvl == 0) ? 16 : ((lvl == 1) ? 8 : 4);
        int cs  = (lvl == 0) ? 8  : ((lvl == 1) ? 4 : 2);
        int bb  = (lvl == 0) ? 0  : ((lvl == 1) ? L1_OFF : L2_OFF);
        int C0  = (lvl == 0) ? C0_0 : ((lvl == 1) ? C0_1 : C0_2);
        float sw = (lvl == 0) ? sw0 : ((lvl == 1) ? sw1 : sw2);
        int rw = iw * 96 + ww - 1;
        float mask = ((unsigned)rw < 480u) ? 1.0f : 0.0f;
        float x  = ((float)rw + 0.5f) * sw - 0.5f;
        float ff = floorf(x);
        float f  = x - ff;
        int w0 = (int)ff;
        int wa = min(max(w0, 0), Wg - 1);
        int wb = min(w0 + 1, Wg - 1);
        s_wl[lvl][ww] = make_float4(__int_as_float(bb + (wa - C0) * cs),
                                    __int_as_float(bb + (wb - C0) * cs), f, mask);
    }

    __syncthreads();   // all staging visible before any compute reads LDS

    // ---- hoist per-thread w-LUT into registers (ww invariant across chunks) ----
    const bool active = tid < 2 * PPAD_W;      // 196 compute threads
    int par = 0, oA0 = 0, oB0 = 0, oA1 = 0, oB1 = 0, oA2 = 0, oB2 = 0;
    float fw0 = 0.f, fw1 = 0.f, fw2 = 0.f, mw = 0.f;
    if (active) {
        par = tid >= PPAD_W;
        int ww = tid - PPAD_W * par;
        float4 wl0 = s_wl[0][ww];
        float4 wl1 = s_wl[1][ww];
        float4 wl2 = s_wl[2][ww];
        oA0 = __float_as_int(wl0.x); oB0 = __float_as_int(wl0.y); fw0 = wl0.z;
        oA1 = __float_as_int(wl1.x); oB1 = __float_as_int(wl1.y); fw1 = wl1.z;
        oA2 = __float_as_int(wl2.x); oB2 = __float_as_int(wl2.y); fw2 = wl2.z;
        mw  = wl0.w;
    }

    const int nrows   = min(ROWS_PER_BLOCK, PPAD_H - row0);   // 12 (last block: 8)
    const int nchunks = nrows >> 1;                           // 6 (last block: 4)
    float* outp = out + (size_t)n * ELEMS_PER_PATCH;

    auto compute_chunk = [&](int c, float* __restrict__ buf) {
        if (!active) return;
        const float* V = s_V + (2 * c + par) * RB_STRIDE;
        float4 A0 = *(const float4*)(V + oA0);
        float4 A1 = *(const float4*)(V + oA0 + 4);
        float4 B0 = *(const float4*)(V + oB0);
        float4 B1 = *(const float4*)(V + oB0 + 4);
        float4 C1a = *(const float4*)(V + oA1);
        float4 C1b = *(const float4*)(V + oB1);
        float2 C2a = *(const float2*)(V + oA2);
        float2 C2b = *(const float2*)(V + oB2);
        float r0  = mw * lerpf(A0.x, B0.x, fw0);
        float r1  = mw * lerpf(A0.y, B0.y, fw0);
        float r2  = mw * lerpf(A0.z, B0.z, fw0);
        float r3  = mw * lerpf(A0.w, B0.w, fw0);
        float r4  = mw * lerpf(A1.x, B1.x, fw0);
        float r5  = mw * lerpf(A1.y, B1.y, fw0);
        float r6  = mw * lerpf(A1.z, B1.z, fw0);
        float r7  = mw * lerpf(A1.w, B1.w, fw0);
        float r8  = mw * lerpf(C1a.x, C1b.x, fw1);
        float r9  = mw * lerpf(C1a.y, C1b.y, fw1);
        float r10 = mw * lerpf(C1a.z, C1b.z, fw1);
        float r11 = mw * lerpf(C1a.w, C1b.w, fw1);
        float r12 = mw * lerpf(C2a.x, C2b.x, fw2);
        float r13 = mw * lerpf(C2a.y, C2b.y, fw2);
        float2* b = (float2*)(buf + tid * CH);
        b[0] = make_float2(r0,  r1);
        b[1] = make_float2(r2,  r3);
        b[2] = make_float2(r4,  r5);
        b[3] = make_float2(r6,  r7);
        b[4] = make_float2(r8,  r9);
        b[5] = make_float2(r10, r11);
        b[6] = make_float2(r12, r13);
    };

    // ---- double-buffered pipeline: store chunk c-1 while computing chunk c ----
    compute_chunk(0, s_bufA);
    __syncthreads();
    for (int c = 1; c < nchunks; ++c) {
        float* prev = (c & 1) ? s_bufA : s_bufB;   // buffer of chunk c-1
        float* cur  = (c & 1) ? s_bufB : s_bufA;
        const float4* sb = (const float4*)prev;
        float4* gb = (float4*)(outp + (size_t)(row0 + 2 * (c - 1)) * ELEMS_PER_ROW);
        for (int j = tid; j < F4_PER_CHUNK; j += 256) gb[j] = sb[j];
        compute_chunk(c, cur);
        __syncthreads();
    }
    {
        float* last = ((nchunks - 1) & 1) ? s_bufB : s_bufA;
        const float4* sb = (const float4*)last;
        float4* gb = (float4*)(outp + (size_t)(row0 + 2 * (nchunks - 1)) * ELEMS_PER_ROW);
        for (int j = tid; j < F4_PER_CHUNK; j += 256) gb[j] = sb[j];
    }
}

extern "C" void kernel_launch(void* const* d_in, const int* in_sizes, int n_in,
                              void* d_out, int out_size, void* d_ws, size_t ws_size,
                              hipStream_t stream) {
    const int*   idx = (const int*)  d_in[0];
    const float* g0  = (const float*)d_in[3];
    const float* g1  = (const float*)d_in[4];
    const float* g2  = (const float*)d_in[5];
    float* out = (float*)d_out;

    dim3 grid(BLOCKS_PER_PATCH, N_PATCH);   // (8, 64) = 512 blocks = 2/CU
    embed_kernel<<<grid, 256, 0, stream>>>(idx, g0, g1, g2, out);
}

// Round 9
// 13.596 us; speedup vs baseline: 1.1047x; 1.1047x over previous
//
#include <hip/hip_runtime.h>
#include <math.h>

// ---- problem constants ----
// SIZE=(60,270,480); CHANNELS=14; GRIDS: (60,16,16,8),(30,8,8,4),(15,4,4,2)
// IDX_MAX=(60,3,5) -> patch=(1,90,96); PADDING=(0,1,1) -> ppad=(1,92,98)
// t_embed: [64][1][92][98][14] = 8,078,336 f32 ; t_manip: [64][16]

#define N_PATCH 64
#define PPAD_H 92
#define PPAD_W 98
#define CH 14
#define ROWS_PER_BLOCK 4
#define BLOCKS_PER_PATCH 23                    // 23*4 = 92 rows exact
#define ELEMS_PER_ROW (PPAD_W * CH)            // 1372
#define ELEMS_PER_PATCH (PPAD_H * ELEMS_PER_ROW)
#define TOTAL_EMBED (N_PATCH * ELEMS_PER_PATCH)
#define TOTAL_MANIP (N_PATCH * 16)

// per-row V-record layout (elements): L0 [0,48)=6cells*8ch, L1 [48,64)=4*4, L2 [64,70)=3*2
#define RB_STRIDE 72   // padded, 16B-aligned rows
#define L1_OFF 48
#define L2_OFF 64
#define V_ENTRIES (ROWS_PER_BLOCK * 70)        // 280 > 256: MUST be a strided loop

__device__ __forceinline__ float lerpf(float a, float b, float f) {
    return a + f * (b - a);
}

// first (leftmost) clamped w-cell for this patch at a given level
__device__ __forceinline__ int wcell0(int rw0, float sw, int Wg) {
    float x = ((float)rw0 + 0.5f) * sw - 0.5f;
    int w0 = (int)floorf(x);
    return min(max(w0, 0), Wg - 1);
}

__global__ __launch_bounds__(256) void embed_kernel(
    const int* __restrict__ idx,
    const float* __restrict__ g0,
    const float* __restrict__ g1,
    const float* __restrict__ g2,
    float* __restrict__ out)
{
    __shared__ __align__(16) float s_V[ROWS_PER_BLOCK * RB_STRIDE];  // 1.1 KB
    __shared__ float4 s_wl[3][PPAD_W];                               // 4.7 KB
    __shared__ __align__(16) float s_buf[4 * 64 * CH];               // 14.3 KB, wave-private quarters

    const int tid = threadIdx.x;
    const int bx  = blockIdx.x;
    const int n   = blockIdx.y;
    const int it  = idx[3 * n + 0];
    const int ih  = idx[3 * n + 1];
    const int iw  = idx[3 * n + 2];
    const int rw0 = iw * 96 - 1;
    const int row0 = bx * ROWS_PER_BLOCK;

    const float sw0 = (float)((double)16 / 480.0);
    const float sw1 = (float)((double)8  / 480.0);
    const float sw2 = (float)((double)4  / 480.0);
    const float sh0 = (float)((double)16 / 270.0);
    const float sh1 = (float)((double)8  / 270.0);
    const float sh2 = (float)((double)4  / 270.0);

    // ---- fused manip (one block only) ----
    if (bx == 0 && n == 0) {
        float* om = out + TOTAL_EMBED;
        for (int e = tid; e < TOTAL_MANIP; e += 256) {
            int nn = e >> 4;
            int j  = e & 15;
            int l  = j & 7;
            float base = (float)M_PI * (float)(1 << l);  // fl32(2^l*pi), pow2 exact
            float v = (float)idx[3 * nn + 0] * base;     // f32 mul = reference
            double dv = (double)v;
            om[e] = (float)((j < 8) ? sin(dv) : cos(dv));
        }
    }

    // ---- build per-row V tables for 4 rows (h,t-lerped, row-mask folded) ----
    // NOTE: V_ENTRIES=280 > blockDim=256 -> strided loop (round-8 bug was `if (tid<280)`)
    const int C0_0 = wcell0(rw0, sw0, 16);
    const int C0_1 = wcell0(rw0, sw1, 8);
    const int C0_2 = wcell0(rw0, sw2, 4);
    for (int e = tid; e < V_ENTRIES; e += 256) {
        int row = e / 70;
        int off = e - 70 * row;
        int rh  = ih * 90 + row0 + row - 1;
        float mh = ((unsigned)rh < 270u) ? 1.0f : 0.0f;
        float v;
        if (off < L1_OFF) {
            // L0: 6 cells x 8 ch; T identity (t = it exactly), h-lerp only
            int cell = off >> 3, chn = off & 7;
            float xh = ((float)rh + 0.5f) * sh0 - 0.5f;
            float ff = floorf(xh);
            float fh = xh - ff;
            int h0 = (int)ff;
            int h0c = min(max(h0, 0), 15), h1c = min(h0 + 1, 15);
            int cw = min(C0_0 + cell, 15);
            const float* base = g0 + (size_t)it * 2048;
            float a = base[(h0c * 16 + cw) * 8 + chn];
            float b = base[(h1c * 16 + cw) * 8 + chn];
            v = mh * lerpf(a, b, fh);
        } else if (off < L2_OFF) {
            // L1: 4 cells x 4 ch; t-lerp + h-lerp
            int o = off - L1_OFF;
            int cell = o >> 2, chn = o & 3;
            float xh = ((float)rh + 0.5f) * sh1 - 0.5f;
            float ff = floorf(xh);
            float fh = xh - ff;
            int h0 = (int)ff;
            int h0c = min(max(h0, 0), 7), h1c = min(h0 + 1, 7);
            float xt = ((float)it + 0.5f) * 0.5f - 0.5f;   // 30/60 exact
            float ftf = floorf(xt);
            float ft  = xt - ftf;
            int t0 = (int)ftf;
            int t0c = min(max(t0, 0), 29), t1c = min(t0 + 1, 29);
            int cw = min(C0_1 + cell, 7);
            float a00 = g1[((t0c * 8 + h0c) * 8 + cw) * 4 + chn];
            float a01 = g1[((t0c * 8 + h1c) * 8 + cw) * 4 + chn];
            float a10 = g1[((t1c * 8 + h0c) * 8 + cw) * 4 + chn];
            float a11 = g1[((t1c * 8 + h1c) * 8 + cw) * 4 + chn];
            v = mh * lerpf(lerpf(a00, a01, fh), lerpf(a10, a11, fh), ft);
        } else {
            // L2: 3 cells x 2 ch
            int o = off - L2_OFF;
            int cell = o >> 1, chn = o & 1;
            float xh = ((float)rh + 0.5f) * sh2 - 0.5f;
            float ff = floorf(xh);
            float fh = xh - ff;
            int h0 = (int)ff;
            int h0c = min(max(h0, 0), 3), h1c = min(h0 + 1, 3);
            float xt = ((float)it + 0.5f) * 0.25f - 0.5f;  // 15/60 exact
            float ftf = floorf(xt);
            float ft  = xt - ftf;
            int t0 = (int)ftf;
            int t0c = min(max(t0, 0), 14), t1c = min(t0 + 1, 14);
            int cw = min(C0_2 + cell, 3);
            float a00 = g2[((t0c * 4 + h0c) * 4 + cw) * 2 + chn];
            float a01 = g2[((t0c * 4 + h1c) * 4 + cw) * 2 + chn];
            float a10 = g2[((t1c * 4 + h0c) * 4 + cw) * 2 + chn];
            float a11 = g2[((t1c * 4 + h1c) * 4 + cw) * 2 + chn];
            v = mh * lerpf(lerpf(a00, a01, fh), lerpf(a10, a11, fh), ft);
        }
        s_V[row * RB_STRIDE + off] = v;
    }

    // ---- per-w LUT: (offA, offB, fw, mask) per level, offsets into V record ----
    for (int i = tid; i < 3 * PPAD_W; i += 256) {
        int lvl = (i >= PPAD_W) + (i >= 2 * PPAD_W);
        int ww  = i - PPAD_W * lvl;
        int Wg  = (lvl == 0) ? 16 : ((lvl == 1) ? 8 : 4);
        int cs  = (lvl == 0) ? 8  : ((lvl == 1) ? 4 : 2);
        int bb  = (lvl == 0) ? 0  : ((lvl == 1) ? L1_OFF : L2_OFF);
        int C0  = (lvl == 0) ? C0_0 : ((lvl == 1) ? C0_1 : C0_2);
        float sw = (lvl == 0) ? sw0 : ((lvl == 1) ? sw1 : sw2);
        int rw = iw * 96 + ww - 1;
        float mask = ((unsigned)rw < 480u) ? 1.0f : 0.0f;
        float x  = ((float)rw + 0.5f) * sw - 0.5f;
        float ff = floorf(x);
        float f  = x - ff;
        int w0 = (int)ff;
        int wa = min(max(w0, 0), Wg - 1);
        int wb = min(w0 + 1, Wg - 1);
        s_wl[lvl][ww] = make_float4(__int_as_float(bb + (wa - C0) * cs),
                                    __int_as_float(bb + (wb - C0) * cs), f, mask);
    }

    __syncthreads();   // ONLY block barrier: staging visible to all waves

    // ---- wave-autonomous: wave w owns row row0+w; no block barriers below ----
    const int wv   = tid >> 6;
    const int lane = tid & 63;
    float* lbuf = s_buf + wv * (64 * CH);          // wave-private 3.6 KB
    const float* V = s_V + wv * RB_STRIDE;
    float* orow = out + (size_t)n * ELEMS_PER_PATCH
                      + (size_t)(row0 + wv) * ELEMS_PER_ROW;

    #pragma unroll
    for (int s = 0; s < 2; ++s) {
        // guard buffer reuse: prior iteration's LDS reads (for stores) have landed
        asm volatile("s_waitcnt lgkmcnt(0)" ::: "memory");
        __builtin_amdgcn_sched_barrier(0);
        int ww = s * 64 + lane;
        if (ww < PPAD_W) {
            float4 wl0 = s_wl[0][ww];
            float4 wl1 = s_wl[1][ww];
            float4 wl2 = s_wl[2][ww];
            int oA0 = __float_as_int(wl0.x), oB0 = __float_as_int(wl0.y);
            int oA1 = __float_as_int(wl1.x), oB1 = __float_as_int(wl1.y);
            int oA2 = __float_as_int(wl2.x), oB2 = __float_as_int(wl2.y);
            float fw0 = wl0.z, fw1 = wl1.z, fw2 = wl2.z, mw = wl0.w;

            float4 A0  = *(const float4*)(V + oA0);
            float4 A1  = *(const float4*)(V + oA0 + 4);
            float4 B0  = *(const float4*)(V + oB0);
            float4 B1  = *(const float4*)(V + oB0 + 4);
            float4 C1a = *(const float4*)(V + oA1);
            float4 C1b = *(const float4*)(V + oB1);
            float2 C2a = *(const float2*)(V + oA2);
            float2 C2b = *(const float2*)(V + oB2);

            float2* b = (float2*)(lbuf + lane * CH);
            b[0] = make_float2(mw * lerpf(A0.x, B0.x, fw0),
                               mw * lerpf(A0.y, B0.y, fw0));
            b[1] = make_float2(mw * lerpf(A0.z, B0.z, fw0),
                               mw * lerpf(A0.w, B0.w, fw0));
            b[2] = make_float2(mw * lerpf(A1.x, B1.x, fw0),
                               mw * lerpf(A1.y, B1.y, fw0));
            b[3] = make_float2(mw * lerpf(A1.z, B1.z, fw0),
                               mw * lerpf(A1.w, B1.w, fw0));
            b[4] = make_float2(mw * lerpf(C1a.x, C1b.x, fw1),
                               mw * lerpf(C1a.y, C1b.y, fw1));
            b[5] = make_float2(mw * lerpf(C1a.z, C1b.z, fw1),
                               mw * lerpf(C1a.w, C1b.w, fw1));
            b[6] = make_float2(mw * lerpf(C2a.x, C2b.x, fw2),
                               mw * lerpf(C2a.y, C2b.y, fw2));
        }
        __builtin_amdgcn_wave_barrier();
        // within-wave write->read ordering: all ds_writes committed before reads
        asm volatile("s_waitcnt lgkmcnt(0)" ::: "memory");
        __builtin_amdgcn_sched_barrier(0);

        const int npx = (s == 0) ? 64 : (PPAD_W - 64);   // 64 / 34
        const int nf4 = npx * CH / 4;                    // 224 / 119
        const float4* sb = (const float4*)lbuf;
        float4* gb = (float4*)(orow + s * 64 * CH);
        for (int j = lane; j < nf4; j += 64) gb[j] = sb[j];
        __builtin_amdgcn_wave_barrier();
    }
}

extern "C" void kernel_launch(void* const* d_in, const int* in_sizes, int n_in,
                              void* d_out, int out_size, void* d_ws, size_t ws_size,
                              hipStream_t stream) {
    const int*   idx = (const int*)  d_in[0];
    const float* g0  = (const float*)d_in[3];
    const float* g1  = (const float*)d_in[4];
    const float* g2  = (const float*)d_in[5];
    float* out = (float*)d_out;

    dim3 grid(BLOCKS_PER_PATCH, N_PATCH);   // (23, 64) = 1472 blocks ~ 5.75/CU
    embed_kernel<<<grid, 256, 0, stream>>>(idx, g0, g1, g2, out);
}

// Round 10
// 12.637 us; speedup vs baseline: 1.1886x; 1.0760x over previous
//
#include <hip/hip_runtime.h>
#include <math.h>

// ---- problem constants ----
// SIZE=(60,270,480); CHANNELS=14; GRIDS: (60,16,16,8),(30,8,8,4),(15,4,4,2)
// IDX_MAX=(60,3,5) -> patch=(1,90,96); PADDING=(0,1,1) -> ppad=(1,92,98)
// t_embed: [64][1][92][98][14] = 8,078,336 f32 ; t_manip: [64][16]

#define N_PATCH 64
#define PPAD_H 92
#define PPAD_W 98
#define CH 14
#define PIX_PER_PATCH (PPAD_H * PPAD_W)        // 9016
#define ROWS_PER_BLOCK 2
#define BLOCKS_PER_PATCH 46                    // 46*2 = 92 rows
#define PX_PER_BLOCK 196                       // 2 rows * 98
#define F4_PER_BLOCK (PX_PER_BLOCK * CH / 4)   // 686
#define ELEMS_PER_PATCH (PIX_PER_PATCH * CH)   // 126224
#define ELEMS_PER_BLOCK (PX_PER_BLOCK * CH)    // 2744
#define TOTAL_EMBED (N_PATCH * ELEMS_PER_PATCH)
#define TOTAL_MANIP (N_PATCH * 16)

// per-row V-record layout (elements): L0 [0,48)=6cells*8ch, L1 [48,64)=4*4, L2 [64,70)=3*2
#define RB_STRIDE 72   // padded to keep rows 16B-aligned
#define L1_OFF 48
#define L2_OFF 64

__device__ __forceinline__ float lerpf(float a, float b, float f) {
    return a + f * (b - a);
}

// first (leftmost) clamped w-cell for this patch at a given level
__device__ __forceinline__ int wcell0(int rw0, float sw, int Wg) {
    float x = ((float)rw0 + 0.5f) * sw - 0.5f;
    int w0 = (int)floorf(x);
    return min(max(w0, 0), Wg - 1);
}

__global__ __launch_bounds__(256) void embed_kernel(
    const int* __restrict__ idx,
    const float* __restrict__ g0,
    const float* __restrict__ g1,
    const float* __restrict__ g2,
    float* __restrict__ out)
{
    __shared__ __align__(16) float s_V[ROWS_PER_BLOCK * RB_STRIDE];  // 576 B
    __shared__ __align__(16) float s_buf[PX_PER_BLOCK * CH];         // 11 KB

    const int tid = threadIdx.x;
    const int bx  = blockIdx.x;
    const int n   = blockIdx.y;
    const int it  = idx[3 * n + 0];
    const int ih  = idx[3 * n + 1];
    const int iw  = idx[3 * n + 2];
    const int rw0 = iw * 96 - 1;

    const float sw0 = (float)((double)16 / 480.0);
    const float sw1 = (float)((double)8  / 480.0);
    const float sw2 = (float)((double)4  / 480.0);
    const float sh0 = (float)((double)16 / 270.0);
    const float sh1 = (float)((double)8  / 270.0);
    const float sh2 = (float)((double)4  / 270.0);

    const int C0_0 = wcell0(rw0, sw0, 16);
    const int C0_1 = wcell0(rw0, sw1, 8);
    const int C0_2 = wcell0(rw0, sw2, 4);

    // ---- fused manip (one block only) ----
    if (bx == 0 && n == 0) {
        float* om = out + TOTAL_EMBED;
        for (int e = tid; e < TOTAL_MANIP; e += 256) {
            int nn = e >> 4;
            int j  = e & 15;
            int l  = j & 7;
            float base = (float)M_PI * (float)(1 << l);  // fl32(2^l*pi), pow2 exact
            float v = (float)idx[3 * nn + 0] * base;     // f32 mul = reference
            double dv = (double)v;
            om[e] = (float)((j < 8) ? sin(dv) : cos(dv));
        }
    }

    // ---- build per-row V tables (h,t-lerped, row-mask folded), 140 entries ----
    if (tid < 96) {
        // L0: 2 rows x 6 cells x 8 ch; T identity (t = it exactly)
        int chn  = tid & 7;
        int u    = tid >> 3;          // 0..11
        int row  = (u >= 6);
        int cell = u - 6 * row;
        int rh   = ih * 90 + (bx * 2 + row) - 1;
        float mh = ((unsigned)rh < 270u) ? 1.0f : 0.0f;
        float xh = ((float)rh + 0.5f) * sh0 - 0.5f;
        float ff = floorf(xh);
        float fh = xh - ff;
        int h0 = (int)ff;
        int h0c = min(max(h0, 0), 15), h1c = min(h0 + 1, 15);
        int cw = min(C0_0 + cell, 15);
        const float* base = g0 + (size_t)it * 2048;
        float a = base[(h0c * 16 + cw) * 8 + chn];
        float b = base[(h1c * 16 + cw) * 8 + chn];
        s_V[row * RB_STRIDE + cell * 8 + chn] = mh * lerpf(a, b, fh);
    } else if (tid < 128) {
        // L1: 2 rows x 4 cells x 4 ch; t-lerp + h-lerp
        int i    = tid - 96;          // 0..31
        int chn  = i & 3;
        int u    = i >> 2;            // 0..7
        int row  = (u >= 4);
        int cell = u - 4 * row;
        int rh   = ih * 90 + (bx * 2 + row) - 1;
        float mh = ((unsigned)rh < 270u) ? 1.0f : 0.0f;
        float xh = ((float)rh + 0.5f) * sh1 - 0.5f;
        float ff = floorf(xh);
        float fh = xh - ff;
        int h0 = (int)ff;
        int h0c = min(max(h0, 0), 7), h1c = min(h0 + 1, 7);
        float xt = ((float)it + 0.5f) * 0.5f - 0.5f;     // 30/60 exact
        float ftf = floorf(xt);
        float ft  = xt - ftf;
        int t0 = (int)ftf;
        int t0c = min(max(t0, 0), 29), t1c = min(t0 + 1, 29);
        int cw = min(C0_1 + cell, 7);
        float a00 = g1[((t0c * 8 + h0c) * 8 + cw) * 4 + chn];
        float a01 = g1[((t0c * 8 + h1c) * 8 + cw) * 4 + chn];
        float a10 = g1[((t1c * 8 + h0c) * 8 + cw) * 4 + chn];
        float a11 = g1[((t1c * 8 + h1c) * 8 + cw) * 4 + chn];
        s_V[row * RB_STRIDE + L1_OFF + cell * 4 + chn] =
            mh * lerpf(lerpf(a00, a01, fh), lerpf(a10, a11, fh), ft);
    } else if (tid < 140) {
        // L2: 2 rows x 3 cells x 2 ch
        int i    = tid - 128;         // 0..11
        int chn  = i & 1;
        int u    = i >> 1;            // 0..5
        int row  = (u >= 3);
        int cell = u - 3 * row;
        int rh   = ih * 90 + (bx * 2 + row) - 1;
        float mh = ((unsigned)rh < 270u) ? 1.0f : 0.0f;
        float xh = ((float)rh + 0.5f) * sh2 - 0.5f;
        float ff = floorf(xh);
        float fh = xh - ff;
        int h0 = (int)ff;
        int h0c = min(max(h0, 0), 3), h1c = min(h0 + 1, 3);
        float xt = ((float)it + 0.5f) * 0.25f - 0.5f;    // 15/60 exact
        float ftf = floorf(xt);
        float ft  = xt - ftf;
        int t0 = (int)ftf;
        int t0c = min(max(t0, 0), 14), t1c = min(t0 + 1, 14);
        int cw = min(C0_2 + cell, 3);
        float a00 = g2[((t0c * 4 + h0c) * 4 + cw) * 2 + chn];
        float a01 = g2[((t0c * 4 + h1c) * 4 + cw) * 2 + chn];
        float a10 = g2[((t1c * 4 + h0c) * 4 + cw) * 2 + chn];
        float a11 = g2[((t1c * 4 + h1c) * 4 + cw) * 2 + chn];
        s_V[row * RB_STRIDE + L2_OFF + cell * 2 + chn] =
            mh * lerpf(lerpf(a00, a01, fh), lerpf(a10, a11, fh), ft);
    }

    __syncthreads();   // V staged; w-LUT is computed in registers below

    // ---- per-pixel: w offsets/fracs in REGISTERS (no LDS LUT), 14 ch compute ----
    if (tid < PX_PER_BLOCK) {
        int row = (tid >= PPAD_W);
        int ww  = tid - PPAD_W * row;
        int rw  = iw * 96 + ww - 1;
        float mw = ((unsigned)rw < 480u) ? 1.0f : 0.0f;
        float rwc = (float)rw + 0.5f;

        // level 0 offsets
        float x0 = rwc * sw0 - 0.5f;
        float f0f = floorf(x0);
        float fw0 = x0 - f0f;
        int w00 = (int)f0f;
        int oA0 = (min(max(w00, 0), 15) - C0_0) * 8;
        int oB0 = (min(w00 + 1, 15)    - C0_0) * 8;
        // level 1
        float x1 = rwc * sw1 - 0.5f;
        float f1f = floorf(x1);
        float fw1 = x1 - f1f;
        int w01 = (int)f1f;
        int oA1 = L1_OFF + (min(max(w01, 0), 7) - C0_1) * 4;
        int oB1 = L1_OFF + (min(w01 + 1, 7)     - C0_1) * 4;
        // level 2
        float x2 = rwc * sw2 - 0.5f;
        float f2f = floorf(x2);
        float fw2 = x2 - f2f;
        int w02 = (int)f2f;
        int oA2 = L2_OFF + (min(max(w02, 0), 3) - C0_2) * 2;
        int oB2 = L2_OFF + (min(w02 + 1, 3)     - C0_2) * 2;

        const float* V = s_V + row * RB_STRIDE;
        float4 A0  = *(const float4*)(V + oA0);
        float4 A1  = *(const float4*)(V + oA0 + 4);
        float4 B0  = *(const float4*)(V + oB0);
        float4 B1  = *(const float4*)(V + oB0 + 4);
        float4 C1a = *(const float4*)(V + oA1);
        float4 C1b = *(const float4*)(V + oB1);
        float2 C2a = *(const float2*)(V + oA2);
        float2 C2b = *(const float2*)(V + oB2);

        float2* b = (float2*)(s_buf + tid * CH);
        b[0] = make_float2(mw * lerpf(A0.x, B0.x, fw0),
                           mw * lerpf(A0.y, B0.y, fw0));
        b[1] = make_float2(mw * lerpf(A0.z, B0.z, fw0),
                           mw * lerpf(A0.w, B0.w, fw0));
        b[2] = make_float2(mw * lerpf(A1.x, B1.x, fw0),
                           mw * lerpf(A1.y, B1.y, fw0));
        b[3] = make_float2(mw * lerpf(A1.z, B1.z, fw0),
                           mw * lerpf(A1.w, B1.w, fw0));
        b[4] = make_float2(mw * lerpf(C1a.x, C1b.x, fw1),
                           mw * lerpf(C1a.y, C1b.y, fw1));
        b[5] = make_float2(mw * lerpf(C1a.z, C1b.z, fw1),
                           mw * lerpf(C1a.w, C1b.w, fw1));
        b[6] = make_float2(mw * lerpf(C2a.x, C2b.x, fw2),
                           mw * lerpf(C2a.y, C2b.y, fw2));
    }
    __syncthreads();

    // ---- coalesced store: 686 float4 = 2744 floats (16B-aligned base) ----
    const float4* sb = (const float4*)s_buf;
    float4* gb = (float4*)(out + (size_t)n * ELEMS_PER_PATCH + bx * ELEMS_PER_BLOCK);
    for (int j = tid; j < F4_PER_BLOCK; j += 256) gb[j] = sb[j];
}

extern "C" void kernel_launch(void* const* d_in, const int* in_sizes, int n_in,
                              void* d_out, int out_size, void* d_ws, size_t ws_size,
                              hipStream_t stream) {
    const int*   idx = (const int*)  d_in[0];
    const float* g0  = (const float*)d_in[3];
    const float* g1  = (const float*)d_in[4];
    const float* g2  = (const float*)d_in[5];
    float* out = (float*)d_out;

    dim3 grid(BLOCKS_PER_PATCH, N_PATCH);   // (46, 64) = 2944 blocks
    embed_kernel<<<grid, 256, 0, stream>>>(idx, g0, g1, g2, out);
}